// Round 9
// baseline (488.587 us; speedup 1.0000x reference)
//
#include <hip/hip_runtime.h>

#define N_NODES 100000
#define N_EDGES 1600000
#define F_IN    501
#define H1      8
#define C1      8
#define D1      64   // H1*C1
#define NCLS    40

typedef __attribute__((ext_vector_type(8))) short bf16x8;
typedef __attribute__((ext_vector_type(8))) unsigned short u16x8;
typedef __attribute__((ext_vector_type(4))) float f32x4;

__device__ __forceinline__ float lrelu(float x) { return x > 0.f ? x : 0.2f * x; }

__device__ __forceinline__ unsigned short f2bf(float f) {
    unsigned u = __float_as_uint(f);
    u += 0x7FFFu + ((u >> 16) & 1u);
    return (unsigned short)(u >> 16);
}
__device__ __forceinline__ float bf2f(unsigned short u) {
    return __uint_as_float(((unsigned)u) << 16);
}

// ---------------------------------------------------------------------------
// GEMM1 (MFMA bf16, barrier-free K-loop):
//   xh1b[N,64] = bf16( x[N,501] @ W1[501,64] )
// W1 staged ONCE into LDS as bf16 [64 cols][512 k] with XOR swizzle (64 KB).
// 8 waves/block, each wave owns 16 rows; A streams per-lane from global with
// depth-4 register prefetch (nontemporal: x has zero reuse).
// ---------------------------------------------------------------------------
__global__ __launch_bounds__(512) void gemm1(const float* __restrict__ x,
                                             const float* __restrict__ W1,
                                             unsigned short* __restrict__ xh1b) {
    __shared__ unsigned short Bs[64 * 512];   // 64 KB, [col][k], swizzled

    const int tid = threadIdx.x;

    // ---- one-time B staging: W1[k][n] -> Bs[n][k] (bf16, swizzled) ----
    for (int i = tid; i < F_IN * 64; i += 512) {
        int k = i >> 6, n = i & 63;           // coalesced read of W1
        int byte = (n << 10) + (k << 1);
        byte ^= (n & 7) << 4;
        Bs[byte >> 1] = f2bf(W1[i]);
    }
    if (tid < 64) {                            // zero tail k = 501..511
        #pragma unroll
        for (int k = F_IN; k < 512; ++k) {
            int byte = (tid << 10) + (k << 1);
            byte ^= (tid & 7) << 4;
            Bs[byte >> 1] = 0;
        }
    }
    __syncthreads();                           // the only barrier

    const int lane = tid & 63;
    const int wave = tid >> 6;
    const int lr   = lane & 15;                // A row / B col within frag
    const int hi   = lane >> 4;                // 0..3
    const int lk   = hi * 8;                   // k offset within 32-step

    const int row  = blockIdx.x * 128 + wave * 16 + lr;
    const int rowc = row < N_NODES ? row : N_NODES - 1;   // clamp (stores guarded)
    const float* aptr = x + (size_t)rowc * F_IN + lk;

    f32x4 acc[4] = {};
    float av[4][8];

    // prefetch K-steps 0..3
    #pragma unroll
    for (int pf = 0; pf < 4; ++pf)
        #pragma unroll
        for (int j = 0; j < 8; ++j)
            av[pf][j] = __builtin_nontemporal_load(aptr + pf * 32 + j);

    #pragma unroll
    for (int s = 0; s < 16; ++s) {
        // convert this step's A fragment to bf16
        bf16x8 a;
        #pragma unroll
        for (int j = 0; j < 8; ++j) a[j] = (short)f2bf(av[s & 3][j]);

        // prefetch step s+4 (loads stay in flight under the MFMAs)
        if (s + 4 < 15) {
            #pragma unroll
            for (int j = 0; j < 8; ++j)
                av[s & 3][j] = __builtin_nontemporal_load(aptr + (s + 4) * 32 + j);
        } else if (s + 4 == 15) {              // tail step: guard k < 501
            #pragma unroll
            for (int j = 0; j < 8; ++j) {
                int k = 15 * 32 + lk + j;
                av[s & 3][j] = (k < F_IN) ? __builtin_nontemporal_load(aptr + 15 * 32 + j) : 0.f;
            }
        }

        // B fragments from LDS (swizzled, conflict-free) + MFMA
        #pragma unroll
        for (int n = 0; n < 4; ++n) {
            int c = n * 16 + lr;
            int byte = (c << 10) + ((s * 32 + lk) << 1);
            byte ^= (c & 7) << 4;
            bf16x8 b = *(const bf16x8*)((const char*)Bs + byte);
            acc[n] = __builtin_amdgcn_mfma_f32_16x16x32_bf16(a, b, acc[n], 0, 0, 0);
        }
    }

    // epilogue: row = base + hi*4 + r, col = n*16 + lr
    int rbase = blockIdx.x * 128 + wave * 16 + hi * 4;
    #pragma unroll
    for (int n = 0; n < 4; ++n) {
        int col = n * 16 + lr;
        #pragma unroll
        for (int r = 0; r < 4; ++r) {
            int grow = rbase + r;
            if (grow < N_NODES) xh1b[(size_t)grow * D1 + col] = f2bf(acc[n][r]);
        }
    }
}

// ---------------------------------------------------------------------------
// A1: per-(node,head) attention coefficients for layer 1 (bf16 features)
// ---------------------------------------------------------------------------
__global__ void a1k(const unsigned short* __restrict__ xh1b,
                    const float* __restrict__ att_s, const float* __restrict__ att_d,
                    const int* __restrict__ idxp,
                    float* __restrict__ a_src, float* __restrict__ a_dst) {
    int gid = blockIdx.x * blockDim.x + threadIdx.x;
    if (gid >= N_NODES * H1) return;
    int n = gid >> 3, h = gid & 7;
    float sign = (idxp[0] == 1) ? -1.f : 1.f;
    uint4 u = *(const uint4*)(xh1b + (size_t)n * D1 + h * C1);
    float v[8];
    v[0] = bf2f((unsigned short)(u.x & 0xffff)); v[1] = bf2f((unsigned short)(u.x >> 16));
    v[2] = bf2f((unsigned short)(u.y & 0xffff)); v[3] = bf2f((unsigned short)(u.y >> 16));
    v[4] = bf2f((unsigned short)(u.z & 0xffff)); v[5] = bf2f((unsigned short)(u.z >> 16));
    v[6] = bf2f((unsigned short)(u.w & 0xffff)); v[7] = bf2f((unsigned short)(u.w >> 16));
    float ss = 0.f, sd = 0.f;
    #pragma unroll
    for (int c = 0; c < C1; ++c) {
        ss += v[c] * att_s[h * C1 + c];
        sd += v[c] * att_d[h * C1 + c];
    }
    a_src[gid] = sign * ss;
    a_dst[gid] = sign * sd;
}

// ---------------------------------------------------------------------------
// CSR build: histogram -> scan -> scatter
// ---------------------------------------------------------------------------
__global__ void k_hist(const int* __restrict__ ei, int* __restrict__ cnt) {
    int e = blockIdx.x * blockDim.x + threadIdx.x;
    if (e >= N_EDGES) return;
    int d = __builtin_nontemporal_load(ei + N_EDGES + e);
    atomicAdd(&cnt[d], 1);
}

__global__ __launch_bounds__(256) void k_scan1(const int* __restrict__ cnt,
                                               int* __restrict__ pre,
                                               int* __restrict__ bsum) {
    __shared__ int s[256];
    int t = threadIdx.x;
    int base = blockIdx.x * 1024 + t * 4;
    int v[4], sum = 0;
    #pragma unroll
    for (int i = 0; i < 4; ++i) {
        v[i] = (base + i < N_NODES) ? cnt[base + i] : 0;
        sum += v[i];
    }
    s[t] = sum;
    __syncthreads();
    for (int off = 1; off < 256; off <<= 1) {
        int x = 0;
        if (t >= off) x = s[t - off];
        __syncthreads();
        if (t >= off) s[t] += x;
        __syncthreads();
    }
    int run = s[t] - sum;
    if (t == 255) bsum[blockIdx.x] = s[255];
    #pragma unroll
    for (int i = 0; i < 4; ++i) {
        if (base + i < N_NODES) pre[base + i] = run;
        run += v[i];
    }
}

__global__ void k_scan2(int* __restrict__ bsum, int nb) {
    __shared__ int s[128];
    int t = threadIdx.x;
    int v = (t < nb) ? bsum[t] : 0;
    s[t] = v;
    __syncthreads();
    for (int off = 1; off < 128; off <<= 1) {
        int x = 0;
        if (t >= off) x = s[t - off];
        __syncthreads();
        if (t >= off) s[t] += x;
        __syncthreads();
    }
    if (t < nb) bsum[t] = s[t] - v;
}

__global__ void k_scan3(const int* __restrict__ pre, const int* __restrict__ bsum,
                        int* __restrict__ rowptr, int* __restrict__ wofs) {
    int i = blockIdx.x * blockDim.x + threadIdx.x;
    if (i < N_NODES) {
        int r = pre[i] + bsum[i >> 10];
        rowptr[i] = r;
        wofs[i]   = r;
    } else if (i == N_NODES) {
        rowptr[N_NODES] = N_EDGES;
    }
}

__global__ void k_scatter(const int* __restrict__ ei, int* __restrict__ wofs,
                          int* __restrict__ ssrc) {
    int e = blockIdx.x * blockDim.x + threadIdx.x;
    if (e >= N_EDGES) return;
    int s = __builtin_nontemporal_load(ei + e);
    int d = __builtin_nontemporal_load(ei + N_EDGES + e);
    int p = atomicAdd(&wofs[d], 1);
    __builtin_nontemporal_store(s, &ssrc[p]);
}

// ---------------------------------------------------------------------------
// AGG1: one wave per destination; 8 edges in flight.
// Lane octet li = lane&7 = head (channels 8li..8li+7); q = lane>>3 = chain.
// ---------------------------------------------------------------------------
__global__ __launch_bounds__(256) void agg1(const int* __restrict__ rowptr,
                                            const int* __restrict__ ssrc,
                                            const unsigned short* __restrict__ xh1b,
                                            const float* __restrict__ a_src,
                                            const float* __restrict__ a_dst,
                                            unsigned short* __restrict__ hb) {
    int wid  = (blockIdx.x * 256 + threadIdx.x) >> 6;
    int lane = threadIdx.x & 63;
    if (wid >= N_NODES) return;
    const int d  = wid;
    const int li = lane & 7;      // head / channel-octet
    const int q  = lane >> 3;     // chain 0..7

    const float adh = a_dst[d * H1 + li];
    float acc[8] = {};
    float den = 0.f;
    if (q == 0) {
        float e0 = __expf(lrelu(a_src[d * H1 + li] + adh));
        u16x8 v = *(const u16x8*)&xh1b[(size_t)d * D1 + (li << 3)];
        #pragma unroll
        for (int j = 0; j < 8; ++j) acc[j] = e0 * bf2f(v[j]);
        den = e0;
    }

    const int beg = rowptr[d], end = rowptr[d + 1];
    for (int p = beg + q; p < end; p += 8) {
        int s = ssrc[p];
        float e = __expf(lrelu(a_src[s * H1 + li] + adh));
        u16x8 v = *(const u16x8*)&xh1b[(size_t)s * D1 + (li << 3)];
        #pragma unroll
        for (int j = 0; j < 8; ++j) acc[j] = fmaf(e, bf2f(v[j]), acc[j]);
        den += e;
    }

    #pragma unroll
    for (int j = 0; j < 8; ++j) {
        acc[j] += __shfl_xor(acc[j], 8);
        acc[j] += __shfl_xor(acc[j], 16);
        acc[j] += __shfl_xor(acc[j], 32);
    }
    den += __shfl_xor(den, 8);
    den += __shfl_xor(den, 16);
    den += __shfl_xor(den, 32);

    if (lane < 8) {
        float inv = 1.f / (den + 1e-16f);
        u16x8 r;
        #pragma unroll
        for (int j = 0; j < 8; ++j) {
            float v = acc[j] * inv;
            v = v > 0.f ? v : (__expf(v) - 1.f);
            r[j] = f2bf(v);
        }
        *(u16x8*)&hb[(size_t)d * D1 + (lane << 3)] = r;
    }
}

// ---------------------------------------------------------------------------
// GEMM2: xh2b[N,40] = bf16( h[N,64] @ W2[64,40] )
// ---------------------------------------------------------------------------
__global__ void gemm2(const unsigned short* __restrict__ hb,
                      const float* __restrict__ W2,
                      unsigned short* __restrict__ xh2b) {
    int gid = blockIdx.x * blockDim.x + threadIdx.x;
    if (gid >= N_NODES * NCLS) return;
    int n = gid / NCLS, c = gid % NCLS;
    const uint4* hr = (const uint4*)(hb + (size_t)n * D1);
    float s = 0.f;
    #pragma unroll
    for (int q = 0; q < 8; ++q) {
        uint4 u = hr[q];
        int k = q * 8;
        s = fmaf(bf2f((unsigned short)(u.x & 0xffff)), W2[(k + 0) * NCLS + c], s);
        s = fmaf(bf2f((unsigned short)(u.x >> 16)),    W2[(k + 1) * NCLS + c], s);
        s = fmaf(bf2f((unsigned short)(u.y & 0xffff)), W2[(k + 2) * NCLS + c], s);
        s = fmaf(bf2f((unsigned short)(u.y >> 16)),    W2[(k + 3) * NCLS + c], s);
        s = fmaf(bf2f((unsigned short)(u.z & 0xffff)), W2[(k + 4) * NCLS + c], s);
        s = fmaf(bf2f((unsigned short)(u.z >> 16)),    W2[(k + 5) * NCLS + c], s);
        s = fmaf(bf2f((unsigned short)(u.w & 0xffff)), W2[(k + 6) * NCLS + c], s);
        s = fmaf(bf2f((unsigned short)(u.w >> 16)),    W2[(k + 7) * NCLS + c], s);
    }
    xh2b[gid] = f2bf(s);
}

// ---------------------------------------------------------------------------
// A2: per-node attention coefficients for layer 2 (bf16 features)
// ---------------------------------------------------------------------------
__global__ void a2k(const unsigned short* __restrict__ xh2b,
                    const float* __restrict__ att_s2, const float* __restrict__ att_d2,
                    const int* __restrict__ idxp,
                    float* __restrict__ a_src2, float* __restrict__ a_dst2) {
    int n = blockIdx.x * blockDim.x + threadIdx.x;
    if (n >= N_NODES) return;
    float sign = (idxp[0] == 1) ? -1.f : 1.f;
    const uint4* xr = (const uint4*)(xh2b + (size_t)n * NCLS);
    float ss = 0.f, sd = 0.f;
    #pragma unroll
    for (int q = 0; q < 5; ++q) {
        uint4 u = xr[q];
        int k = q * 8;
        float v[8];
        v[0] = bf2f((unsigned short)(u.x & 0xffff)); v[1] = bf2f((unsigned short)(u.x >> 16));
        v[2] = bf2f((unsigned short)(u.y & 0xffff)); v[3] = bf2f((unsigned short)(u.y >> 16));
        v[4] = bf2f((unsigned short)(u.z & 0xffff)); v[5] = bf2f((unsigned short)(u.z >> 16));
        v[6] = bf2f((unsigned short)(u.w & 0xffff)); v[7] = bf2f((unsigned short)(u.w >> 16));
        #pragma unroll
        for (int j = 0; j < 8; ++j) {
            ss += v[j] * att_s2[k + j];
            sd += v[j] * att_d2[k + j];
        }
    }
    a_src2[n] = sign * ss;
    a_dst2[n] = sign * sd;
}

// ---------------------------------------------------------------------------
// AGG2: one wave per destination; 8 edges in flight; lane octets, li<5 active
// (channels 8li..8li+7). Fused self-loop, normalize, bias -> out (fp32).
// ---------------------------------------------------------------------------
__global__ __launch_bounds__(256) void agg2(const int* __restrict__ rowptr,
                                            const int* __restrict__ ssrc,
                                            const unsigned short* __restrict__ xh2b,
                                            const float* __restrict__ a_src2,
                                            const float* __restrict__ a_dst2,
                                            const float* __restrict__ bias2,
                                            float* __restrict__ out) {
    int wid  = (blockIdx.x * 256 + threadIdx.x) >> 6;
    int lane = threadIdx.x & 63;
    if (wid >= N_NODES) return;
    const int d  = wid;
    const int li = lane & 7;      // channel-octet, active if li<5
    const int q  = lane >> 3;     // chain 0..7
    const bool act = li < (NCLS / 8);

    const float adh = a_dst2[d];
    float acc[8] = {};
    float den = 0.f;
    if (q == 0) {
        float e0 = __expf(lrelu(a_src2[d] + adh));
        if (act) {
            u16x8 v = *(const u16x8*)&xh2b[(size_t)d * NCLS + (li << 3)];
            #pragma unroll
            for (int j = 0; j < 8; ++j) acc[j] = e0 * bf2f(v[j]);
        }
        den = e0;
    }

    const int beg = rowptr[d], end = rowptr[d + 1];
    for (int p = beg + q; p < end; p += 8) {
        int s = ssrc[p];
        float e = __expf(lrelu(a_src2[s] + adh));
        if (act) {
            u16x8 v = *(const u16x8*)&xh2b[(size_t)s * NCLS + (li << 3)];
            #pragma unroll
            for (int j = 0; j < 8; ++j) acc[j] = fmaf(e, bf2f(v[j]), acc[j]);
        }
        den += e;
    }

    #pragma unroll
    for (int j = 0; j < 8; ++j) {
        acc[j] += __shfl_xor(acc[j], 8);
        acc[j] += __shfl_xor(acc[j], 16);
        acc[j] += __shfl_xor(acc[j], 32);
    }
    den += __shfl_xor(den, 8);
    den += __shfl_xor(den, 16);
    den += __shfl_xor(den, 32);

    if (lane < 5) {
        float inv = 1.f / (den + 1e-16f);
        float4 r0, r1;
        const float* bp = bias2 + (lane << 3);
        r0.x = acc[0] * inv + bp[0];
        r0.y = acc[1] * inv + bp[1];
        r0.z = acc[2] * inv + bp[2];
        r0.w = acc[3] * inv + bp[3];
        r1.x = acc[4] * inv + bp[4];
        r1.y = acc[5] * inv + bp[5];
        r1.z = acc[6] * inv + bp[6];
        r1.w = acc[7] * inv + bp[7];
        float* op = out + (size_t)d * NCLS + (lane << 3);
        *(float4*)op       = r0;
        *(float4*)(op + 4) = r1;
    }
}

// ---------------------------------------------------------------------------
extern "C" void kernel_launch(void* const* d_in, const int* in_sizes, int n_in,
                              void* d_out, int out_size, void* d_ws, size_t ws_size,
                              hipStream_t stream) {
    const float* x    = (const float*)d_in[0];
    const float* W1   = (const float*)d_in[1];
    const float* as1w = (const float*)d_in[2];
    const float* ad1w = (const float*)d_in[3];
    const float* W2   = (const float*)d_in[4];
    const float* as2w = (const float*)d_in[5];
    const float* ad2w = (const float*)d_in[6];
    const float* b2   = (const float*)d_in[7];
    const int*   ei   = (const int*)d_in[8];
    const int*   idxp = (const int*)d_in[9];
    float* out = (float*)d_out;

    // workspace layout
    unsigned short* xh1b = (unsigned short*)d_ws;        // [N*64] bf16
    unsigned short* hb   = xh1b + (size_t)N_NODES * D1;  // [N*64] bf16
    unsigned short* xh2b = hb + (size_t)N_NODES * D1;    // [N*40] bf16
    float* as1 = (float*)(xh2b + (size_t)N_NODES * NCLS);
    float* ad1 = as1 + (size_t)N_NODES * H1;
    float* as2 = ad1 + (size_t)N_NODES * H1;             // [N]
    float* ad2 = as2 + N_NODES;
    int*   cnt    = (int*)(ad2 + N_NODES);               // [N]
    int*   pre    = cnt + N_NODES;                       // [N]
    int*   rowptr = pre + N_NODES;                       // [N+1]
    int*   wofs   = rowptr + (N_NODES + 1);              // [N]
    int*   bsum   = wofs + N_NODES;                      // [128]
    int*   ssrc   = bsum + 128;                          // [E]

    const int NB = (N_NODES + 1023) / 1024;

    // ---- CSR build ----
    hipMemsetAsync(cnt, 0, (size_t)N_NODES * sizeof(int), stream);
    k_hist<<<(N_EDGES + 255) / 256, 256, 0, stream>>>(ei, cnt);
    k_scan1<<<NB, 256, 0, stream>>>(cnt, pre, bsum);
    k_scan2<<<1, 128, 0, stream>>>(bsum, NB);
    k_scan3<<<(N_NODES + 256) / 256, 256, 0, stream>>>(pre, bsum, rowptr, wofs);
    k_scatter<<<(N_EDGES + 255) / 256, 256, 0, stream>>>(ei, wofs, ssrc);

    // ---- layer 1 ----
    gemm1<<<(N_NODES + 127) / 128, 512, 0, stream>>>(x, W1, xh1b);
    a1k<<<(N_NODES * H1 + 255) / 256, 256, 0, stream>>>(xh1b, as1w, ad1w, idxp, as1, ad1);
    agg1<<<(N_NODES * 64 + 255) / 256, 256, 0, stream>>>(rowptr, ssrc, xh1b, as1, ad1, hb);

    // ---- layer 2 ----
    gemm2<<<(N_NODES * NCLS + 255) / 256, 256, 0, stream>>>(hb, W2, xh2b);
    a2k<<<(N_NODES + 255) / 256, 256, 0, stream>>>(xh2b, as2w, ad2w, idxp, as2, ad2);
    agg2<<<(N_NODES * 64 + 255) / 256, 256, 0, stream>>>(rowptr, ssrc, xh2b, as2, ad2, b2, out);
}

// Round 10
// 336.180 us; speedup vs baseline: 1.4534x; 1.4534x over previous
//
#include <hip/hip_runtime.h>

#define N_NODES 100000
#define N_EDGES 1600000
#define F_IN    501
#define H1      8
#define C1      8
#define D1      64   // H1*C1
#define NCLS    40

#define BSH     9                       // bucket = dst >> 9 (512 nodes/bucket)
#define NBUCK   196                     // ceil(N_NODES / 512)
#define BINBLK  256                     // blocks for bc1/bc3

typedef __attribute__((ext_vector_type(8))) short bf16x8;
typedef __attribute__((ext_vector_type(4))) float f32x4;

__device__ __forceinline__ float lrelu(float x) { return x > 0.f ? x : 0.2f * x; }

__device__ __forceinline__ unsigned short f2bf(float f) {
    unsigned u = __float_as_uint(f);
    u += 0x7FFFu + ((u >> 16) & 1u);
    return (unsigned short)(u >> 16);
}
__device__ __forceinline__ float bf2f(unsigned short u) {
    return __uint_as_float(((unsigned)u) << 16);
}

// ---------------------------------------------------------------------------
// GEMM1 (MFMA bf16, barrier-free K-loop) — R8 version (no NT).
// ---------------------------------------------------------------------------
__global__ __launch_bounds__(512) void gemm1(const float* __restrict__ x,
                                             const float* __restrict__ W1,
                                             unsigned short* __restrict__ xh1b) {
    __shared__ unsigned short Bs[64 * 512];   // 64 KB, [col][k], swizzled

    const int tid = threadIdx.x;

    for (int i = tid; i < F_IN * 64; i += 512) {
        int k = i >> 6, n = i & 63;
        int byte = (n << 10) + (k << 1);
        byte ^= (n & 7) << 4;
        Bs[byte >> 1] = f2bf(W1[i]);
    }
    if (tid < 64) {
        #pragma unroll
        for (int k = F_IN; k < 512; ++k) {
            int byte = (tid << 10) + (k << 1);
            byte ^= (tid & 7) << 4;
            Bs[byte >> 1] = 0;
        }
    }
    __syncthreads();

    const int lane = tid & 63;
    const int wave = tid >> 6;
    const int lr   = lane & 15;
    const int hi   = lane >> 4;
    const int lk   = hi * 8;

    const int row  = blockIdx.x * 128 + wave * 16 + lr;
    const int rowc = row < N_NODES ? row : N_NODES - 1;
    const float* aptr = x + (size_t)rowc * F_IN + lk;

    f32x4 acc[4] = {};
    float av[4][8];

    #pragma unroll
    for (int pf = 0; pf < 4; ++pf)
        #pragma unroll
        for (int j = 0; j < 8; ++j)
            av[pf][j] = aptr[pf * 32 + j];

    #pragma unroll
    for (int s = 0; s < 16; ++s) {
        bf16x8 a;
        #pragma unroll
        for (int j = 0; j < 8; ++j) a[j] = (short)f2bf(av[s & 3][j]);

        if (s + 4 < 15) {
            #pragma unroll
            for (int j = 0; j < 8; ++j)
                av[s & 3][j] = aptr[(s + 4) * 32 + j];
        } else if (s + 4 == 15) {
            #pragma unroll
            for (int j = 0; j < 8; ++j) {
                int k = 15 * 32 + lk + j;
                av[s & 3][j] = (k < F_IN) ? aptr[15 * 32 + j] : 0.f;
            }
        }

        #pragma unroll
        for (int n = 0; n < 4; ++n) {
            int c = n * 16 + lr;
            int byte = (c << 10) + ((s * 32 + lk) << 1);
            byte ^= (c & 7) << 4;
            bf16x8 b = *(const bf16x8*)((const char*)Bs + byte);
            acc[n] = __builtin_amdgcn_mfma_f32_16x16x32_bf16(a, b, acc[n], 0, 0, 0);
        }
    }

    int rbase = blockIdx.x * 128 + wave * 16 + hi * 4;
    #pragma unroll
    for (int n = 0; n < 4; ++n) {
        int col = n * 16 + lr;
        #pragma unroll
        for (int r = 0; r < 4; ++r) {
            int grow = rbase + r;
            if (grow < N_NODES) xh1b[(size_t)grow * D1 + col] = f2bf(acc[n][r]);
        }
    }
}

// ---------------------------------------------------------------------------
// A1: per-(node,head) attention coefficients for layer 1 (bf16 features)
// ---------------------------------------------------------------------------
__global__ void a1k(const unsigned short* __restrict__ xh1b,
                    const float* __restrict__ att_s, const float* __restrict__ att_d,
                    const int* __restrict__ idxp,
                    float* __restrict__ a_src, float* __restrict__ a_dst) {
    int gid = blockIdx.x * blockDim.x + threadIdx.x;
    if (gid >= N_NODES * H1) return;
    int n = gid >> 3, h = gid & 7;
    float sign = (idxp[0] == 1) ? -1.f : 1.f;
    uint4 u = *(const uint4*)(xh1b + (size_t)n * D1 + h * C1);
    float v[8];
    v[0] = bf2f((unsigned short)(u.x & 0xffff)); v[1] = bf2f((unsigned short)(u.x >> 16));
    v[2] = bf2f((unsigned short)(u.y & 0xffff)); v[3] = bf2f((unsigned short)(u.y >> 16));
    v[4] = bf2f((unsigned short)(u.z & 0xffff)); v[5] = bf2f((unsigned short)(u.z >> 16));
    v[6] = bf2f((unsigned short)(u.w & 0xffff)); v[7] = bf2f((unsigned short)(u.w >> 16));
    float ss = 0.f, sd = 0.f;
    #pragma unroll
    for (int c = 0; c < C1; ++c) {
        ss += v[c] * att_s[h * C1 + c];
        sd += v[c] * att_d[h * C1 + c];
    }
    a_src[gid] = sign * ss;
    a_dst[gid] = sign * sd;
}

// ---------------------------------------------------------------------------
// CSR build: block-aggregated two-level binning (196 buckets of 512 nodes).
// ---------------------------------------------------------------------------
// bc1: global bucket counts via per-block LDS histogram
__global__ __launch_bounds__(256) void bc1(const int* __restrict__ ei,
                                           int* __restrict__ gcnt) {
    __shared__ int h[NBUCK];
    for (int i = threadIdx.x; i < NBUCK; i += 256) h[i] = 0;
    __syncthreads();
    for (int e = blockIdx.x * 256 + threadIdx.x; e < N_EDGES; e += BINBLK * 256)
        atomicAdd(&h[ei[N_EDGES + e] >> BSH], 1);
    __syncthreads();
    for (int i = threadIdx.x; i < NBUCK; i += 256)
        if (h[i]) atomicAdd(&gcnt[i], h[i]);
}

// bc2: scan bucket counts -> bases + cursors
__global__ __launch_bounds__(256) void bc2(const int* __restrict__ gcnt,
                                           int* __restrict__ bbase,
                                           int* __restrict__ bcur,
                                           int* __restrict__ rowptr) {
    __shared__ int s[256];
    int t = threadIdx.x;
    int v = (t < NBUCK) ? gcnt[t] : 0;
    s[t] = v;
    __syncthreads();
    for (int off = 1; off < 256; off <<= 1) {
        int x = 0;
        if (t >= off) x = s[t - off];
        __syncthreads();
        if (t >= off) s[t] += x;
        __syncthreads();
    }
    if (t < NBUCK) { int e = s[t] - v; bbase[t] = e; bcur[t] = e; }
    if (t == 0)    { bbase[NBUCK] = N_EDGES; rowptr[N_NODES] = N_EDGES; }
}

// bc3: bin edges into bucket-contiguous tmp with per-block reservations.
// packed word: (src << 9) | (dst & 511)   (17 + 9 = 26 bits)
__global__ __launch_bounds__(256) void bc3(const int* __restrict__ ei,
                                           int* __restrict__ bcur,
                                           unsigned* __restrict__ tmp) {
    __shared__ int h[NBUCK];
    __shared__ int base[NBUCK];
    for (int i = threadIdx.x; i < NBUCK; i += 256) h[i] = 0;
    __syncthreads();
    // phase 1: count this block's edges per bucket
    for (int e = blockIdx.x * 256 + threadIdx.x; e < N_EDGES; e += BINBLK * 256)
        atomicAdd(&h[ei[N_EDGES + e] >> BSH], 1);
    __syncthreads();
    // phase 2: reserve contiguous sub-segments
    for (int i = threadIdx.x; i < NBUCK; i += 256) {
        int c = h[i];
        base[i] = c ? atomicAdd(&bcur[i], c) : 0;
        h[i] = 0;                       // reuse as local rank
    }
    __syncthreads();
    // phase 3: write packed edges (sequential per bucket-stream -> dense lines)
    for (int e = blockIdx.x * 256 + threadIdx.x; e < N_EDGES; e += BINBLK * 256) {
        int s = ei[e], d = ei[N_EDGES + e];
        int b = d >> BSH;
        int r = atomicAdd(&h[b], 1);
        tmp[base[b] + r] = ((unsigned)s << BSH) | (unsigned)(d & 511);
    }
}

// bc4: per-bucket (512 nodes): LDS count + scan -> rowptr, node-sorted ssrc.
__global__ __launch_bounds__(256) void bc4(const unsigned* __restrict__ tmp,
                                           const int* __restrict__ bbase,
                                           int* __restrict__ rowptr,
                                           int* __restrict__ ssrc) {
    __shared__ int cnt[512], ofs[512], sc[256];
    const int b = blockIdx.x, t = threadIdx.x;
    const int lo = bbase[b], hi = bbase[b + 1];
    cnt[t] = 0; cnt[t + 256] = 0;
    __syncthreads();
    for (int i = lo + t; i < hi; i += 256)
        atomicAdd(&cnt[tmp[i] & 511], 1);
    __syncthreads();
    // scan 512 via 256 threads x 2 elems
    int v0 = cnt[2 * t], v1 = cnt[2 * t + 1];
    int sum = v0 + v1;
    sc[t] = sum;
    __syncthreads();
    for (int off = 1; off < 256; off <<= 1) {
        int x = 0;
        if (t >= off) x = sc[t - off];
        __syncthreads();
        if (t >= off) sc[t] += x;
        __syncthreads();
    }
    int pre = sc[t] - sum;               // exclusive prefix of elem 2t
    int n0 = (b << BSH) + 2 * t;
    int base0 = lo + pre, base1 = base0 + v0;
    if (n0 < N_NODES)     rowptr[n0]     = base0;
    if (n0 + 1 < N_NODES) rowptr[n0 + 1] = base1;
    ofs[2 * t] = base0; ofs[2 * t + 1] = base1;
    __syncthreads();
    for (int i = lo + t; i < hi; i += 256) {
        unsigned v = tmp[i];
        int p = atomicAdd(&ofs[v & 511], 1);
        ssrc[p] = (int)(v >> BSH);
    }
}

// ---------------------------------------------------------------------------
// AGG1: one wave per destination; 4 edges in flight (quarter-waves).
// ---------------------------------------------------------------------------
__global__ __launch_bounds__(256) void agg1(const int* __restrict__ rowptr,
                                            const int* __restrict__ ssrc,
                                            const unsigned short* __restrict__ xh1b,
                                            const float* __restrict__ a_src,
                                            const float* __restrict__ a_dst,
                                            unsigned short* __restrict__ hb) {
    int wid  = (blockIdx.x * 256 + threadIdx.x) >> 6;
    int lane = threadIdx.x & 63;
    if (wid >= N_NODES) return;
    const int d  = wid;
    const int li = lane & 15;
    const int q  = lane >> 4;
    const int hh = li >> 1;

    const float adh = a_dst[d * H1 + hh];
    float a0 = 0.f, a1 = 0.f, a2 = 0.f, a3 = 0.f, den = 0.f;
    if (q == 0) {
        float e0 = __expf(lrelu(a_src[d * H1 + hh] + adh));
        ushort4 v = *(const ushort4*)&xh1b[(size_t)d * D1 + (li << 2)];
        a0 = e0 * bf2f(v.x); a1 = e0 * bf2f(v.y);
        a2 = e0 * bf2f(v.z); a3 = e0 * bf2f(v.w);
        den = e0;
    }

    const int beg = rowptr[d], end = rowptr[d + 1];
    for (int p = beg + q; p < end; p += 4) {
        int s = ssrc[p];
        float e = __expf(lrelu(a_src[s * H1 + hh] + adh));
        ushort4 v = *(const ushort4*)&xh1b[(size_t)s * D1 + (li << 2)];
        a0 = fmaf(e, bf2f(v.x), a0);
        a1 = fmaf(e, bf2f(v.y), a1);
        a2 = fmaf(e, bf2f(v.z), a2);
        a3 = fmaf(e, bf2f(v.w), a3);
        den += e;
    }

    a0 += __shfl_xor(a0, 16); a0 += __shfl_xor(a0, 32);
    a1 += __shfl_xor(a1, 16); a1 += __shfl_xor(a1, 32);
    a2 += __shfl_xor(a2, 16); a2 += __shfl_xor(a2, 32);
    a3 += __shfl_xor(a3, 16); a3 += __shfl_xor(a3, 32);
    den += __shfl_xor(den, 16); den += __shfl_xor(den, 32);

    if (lane < 16) {
        float inv = 1.f / (den + 1e-16f);
        float v0 = a0 * inv, v1 = a1 * inv, v2 = a2 * inv, v3 = a3 * inv;
        v0 = v0 > 0.f ? v0 : (__expf(v0) - 1.f);
        v1 = v1 > 0.f ? v1 : (__expf(v1) - 1.f);
        v2 = v2 > 0.f ? v2 : (__expf(v2) - 1.f);
        v3 = v3 > 0.f ? v3 : (__expf(v3) - 1.f);
        ushort4 r;
        r.x = f2bf(v0); r.y = f2bf(v1); r.z = f2bf(v2); r.w = f2bf(v3);
        *(ushort4*)&hb[(size_t)d * D1 + (li << 2)] = r;
    }
}

// ---------------------------------------------------------------------------
// GEMM2: xh2b[N,40] = bf16( h[N,64] @ W2[64,40] )
// ---------------------------------------------------------------------------
__global__ void gemm2(const unsigned short* __restrict__ hb,
                      const float* __restrict__ W2,
                      unsigned short* __restrict__ xh2b) {
    int gid = blockIdx.x * blockDim.x + threadIdx.x;
    if (gid >= N_NODES * NCLS) return;
    int n = gid / NCLS, c = gid % NCLS;
    const uint4* hr = (const uint4*)(hb + (size_t)n * D1);
    float s = 0.f;
    #pragma unroll
    for (int q = 0; q < 8; ++q) {
        uint4 u = hr[q];
        int k = q * 8;
        s = fmaf(bf2f((unsigned short)(u.x & 0xffff)), W2[(k + 0) * NCLS + c], s);
        s = fmaf(bf2f((unsigned short)(u.x >> 16)),    W2[(k + 1) * NCLS + c], s);
        s = fmaf(bf2f((unsigned short)(u.y & 0xffff)), W2[(k + 2) * NCLS + c], s);
        s = fmaf(bf2f((unsigned short)(u.y >> 16)),    W2[(k + 3) * NCLS + c], s);
        s = fmaf(bf2f((unsigned short)(u.z & 0xffff)), W2[(k + 4) * NCLS + c], s);
        s = fmaf(bf2f((unsigned short)(u.z >> 16)),    W2[(k + 5) * NCLS + c], s);
        s = fmaf(bf2f((unsigned short)(u.w & 0xffff)), W2[(k + 6) * NCLS + c], s);
        s = fmaf(bf2f((unsigned short)(u.w >> 16)),    W2[(k + 7) * NCLS + c], s);
    }
    xh2b[gid] = f2bf(s);
}

// ---------------------------------------------------------------------------
// A2: per-node attention coefficients for layer 2 (bf16 features)
// ---------------------------------------------------------------------------
__global__ void a2k(const unsigned short* __restrict__ xh2b,
                    const float* __restrict__ att_s2, const float* __restrict__ att_d2,
                    const int* __restrict__ idxp,
                    float* __restrict__ a_src2, float* __restrict__ a_dst2) {
    int n = blockIdx.x * blockDim.x + threadIdx.x;
    if (n >= N_NODES) return;
    float sign = (idxp[0] == 1) ? -1.f : 1.f;
    const uint4* xr = (const uint4*)(xh2b + (size_t)n * NCLS);
    float ss = 0.f, sd = 0.f;
    #pragma unroll
    for (int q = 0; q < 5; ++q) {
        uint4 u = xr[q];
        int k = q * 8;
        float v[8];
        v[0] = bf2f((unsigned short)(u.x & 0xffff)); v[1] = bf2f((unsigned short)(u.x >> 16));
        v[2] = bf2f((unsigned short)(u.y & 0xffff)); v[3] = bf2f((unsigned short)(u.y >> 16));
        v[4] = bf2f((unsigned short)(u.z & 0xffff)); v[5] = bf2f((unsigned short)(u.z >> 16));
        v[6] = bf2f((unsigned short)(u.w & 0xffff)); v[7] = bf2f((unsigned short)(u.w >> 16));
        #pragma unroll
        for (int j = 0; j < 8; ++j) {
            ss += v[j] * att_s2[k + j];
            sd += v[j] * att_d2[k + j];
        }
    }
    a_src2[n] = sign * ss;
    a_dst2[n] = sign * sd;
}

// ---------------------------------------------------------------------------
// AGG2: one wave per destination; 4 edges in flight; fused bias -> out.
// ---------------------------------------------------------------------------
__global__ __launch_bounds__(256) void agg2(const int* __restrict__ rowptr,
                                            const int* __restrict__ ssrc,
                                            const unsigned short* __restrict__ xh2b,
                                            const float* __restrict__ a_src2,
                                            const float* __restrict__ a_dst2,
                                            const float* __restrict__ bias2,
                                            float* __restrict__ out) {
    int wid  = (blockIdx.x * 256 + threadIdx.x) >> 6;
    int lane = threadIdx.x & 63;
    if (wid >= N_NODES) return;
    const int d  = wid;
    const int li = lane & 15;
    const int q  = lane >> 4;
    const bool act = li < (NCLS / 4);

    const float adh = a_dst2[d];
    float a0 = 0.f, a1 = 0.f, a2 = 0.f, a3 = 0.f, den = 0.f;
    if (q == 0) {
        float e0 = __expf(lrelu(a_src2[d] + adh));
        if (act) {
            ushort4 v = *(const ushort4*)&xh2b[(size_t)d * NCLS + (li << 2)];
            a0 = e0 * bf2f(v.x); a1 = e0 * bf2f(v.y);
            a2 = e0 * bf2f(v.z); a3 = e0 * bf2f(v.w);
        }
        den = e0;
    }

    const int beg = rowptr[d], end = rowptr[d + 1];
    for (int p = beg + q; p < end; p += 4) {
        int s = ssrc[p];
        float e = __expf(lrelu(a_src2[s] + adh));
        if (act) {
            ushort4 v = *(const ushort4*)&xh2b[(size_t)s * NCLS + (li << 2)];
            a0 = fmaf(e, bf2f(v.x), a0);
            a1 = fmaf(e, bf2f(v.y), a1);
            a2 = fmaf(e, bf2f(v.z), a2);
            a3 = fmaf(e, bf2f(v.w), a3);
        }
        den += e;
    }

    a0 += __shfl_xor(a0, 16); a0 += __shfl_xor(a0, 32);
    a1 += __shfl_xor(a1, 16); a1 += __shfl_xor(a1, 32);
    a2 += __shfl_xor(a2, 16); a2 += __shfl_xor(a2, 32);
    a3 += __shfl_xor(a3, 16); a3 += __shfl_xor(a3, 32);
    den += __shfl_xor(den, 16); den += __shfl_xor(den, 32);

    if (lane < 16 && act) {
        float inv = 1.f / (den + 1e-16f);
        float4 bv = *(const float4*)&bias2[li << 2];
        float4 r;
        r.x = a0 * inv + bv.x;
        r.y = a1 * inv + bv.y;
        r.z = a2 * inv + bv.z;
        r.w = a3 * inv + bv.w;
        *(float4*)&out[(size_t)d * NCLS + (li << 2)] = r;
    }
}

// ---------------------------------------------------------------------------
extern "C" void kernel_launch(void* const* d_in, const int* in_sizes, int n_in,
                              void* d_out, int out_size, void* d_ws, size_t ws_size,
                              hipStream_t stream) {
    const float* x    = (const float*)d_in[0];
    const float* W1   = (const float*)d_in[1];
    const float* as1w = (const float*)d_in[2];
    const float* ad1w = (const float*)d_in[3];
    const float* W2   = (const float*)d_in[4];
    const float* as2w = (const float*)d_in[5];
    const float* ad2w = (const float*)d_in[6];
    const float* b2   = (const float*)d_in[7];
    const int*   ei   = (const int*)d_in[8];
    const int*   idxp = (const int*)d_in[9];
    float* out = (float*)d_out;

    // workspace layout
    unsigned short* xh1b = (unsigned short*)d_ws;        // [N*64] bf16
    unsigned short* hb   = xh1b + (size_t)N_NODES * D1;  // [N*64] bf16
    unsigned short* xh2b = hb + (size_t)N_NODES * D1;    // [N*40] bf16
    float* as1 = (float*)(xh2b + (size_t)N_NODES * NCLS);
    float* ad1 = as1 + (size_t)N_NODES * H1;
    float* as2 = ad1 + (size_t)N_NODES * H1;             // [N]
    float* ad2 = as2 + N_NODES;
    int* gcnt   = (int*)(ad2 + N_NODES);                 // [NBUCK]
    int* bbase  = gcnt + NBUCK;                          // [NBUCK+1]
    int* bcur   = bbase + (NBUCK + 1);                   // [NBUCK]
    int* rowptr = bcur + NBUCK;                          // [N+1]
    unsigned* tmp = (unsigned*)(rowptr + (N_NODES + 1)); // [E]
    int* ssrc   = (int*)(tmp + N_EDGES);                 // [E]

    // ---- CSR build (block-aggregated two-level binning) ----
    hipMemsetAsync(gcnt, 0, (size_t)NBUCK * sizeof(int), stream);
    bc1<<<BINBLK, 256, 0, stream>>>(ei, gcnt);
    bc2<<<1, 256, 0, stream>>>(gcnt, bbase, bcur, rowptr);
    bc3<<<BINBLK, 256, 0, stream>>>(ei, bcur, tmp);
    bc4<<<NBUCK, 256, 0, stream>>>(tmp, bbase, rowptr, ssrc);

    // ---- layer 1 ----
    gemm1<<<(N_NODES + 127) / 128, 512, 0, stream>>>(x, W1, xh1b);
    a1k<<<(N_NODES * H1 + 255) / 256, 256, 0, stream>>>(xh1b, as1w, ad1w, idxp, as1, ad1);
    agg1<<<(N_NODES * 64 + 255) / 256, 256, 0, stream>>>(rowptr, ssrc, xh1b, as1, ad1, hb);

    // ---- layer 2 ----
    gemm2<<<(N_NODES * NCLS + 255) / 256, 256, 0, stream>>>(hb, W2, xh2b);
    a2k<<<(N_NODES + 255) / 256, 256, 0, stream>>>(xh2b, as2w, ad2w, idxp, as2, ad2);
    agg2<<<(N_NODES * 64 + 255) / 256, 256, 0, stream>>>(rowptr, ssrc, xh2b, as2, ad2, b2, out);
}

// Round 11
// 300.093 us; speedup vs baseline: 1.6281x; 1.1203x over previous
//
#include <hip/hip_runtime.h>

#define N_NODES 100000
#define N_EDGES 1600000
#define F_IN    501
#define H1      8
#define C1      8
#define D1      64   // H1*C1
#define NCLS    40

#define BSH     9                       // bucket = dst >> 9 (512 nodes/bucket)
#define NBUCK   196                     // ceil(N_NODES / 512)
#define BINBLK  256                     // blocks for bc1/bc3

typedef __attribute__((ext_vector_type(8))) short bf16x8;
typedef __attribute__((ext_vector_type(4))) float f32x4;

__device__ __forceinline__ float lrelu(float x) { return x > 0.f ? x : 0.2f * x; }

__device__ __forceinline__ unsigned short f2bf(float f) {
    unsigned u = __float_as_uint(f);
    u += 0x7FFFu + ((u >> 16) & 1u);
    return (unsigned short)(u >> 16);
}
__device__ __forceinline__ float bf2f(unsigned short u) {
    return __uint_as_float(((unsigned)u) << 16);
}

// ---------------------------------------------------------------------------
// GEMM1 (MFMA bf16, barrier-free K-loop) — unchanged from R10.
// ---------------------------------------------------------------------------
__global__ __launch_bounds__(512) void gemm1(const float* __restrict__ x,
                                             const float* __restrict__ W1,
                                             unsigned short* __restrict__ xh1b) {
    __shared__ unsigned short Bs[64 * 512];   // 64 KB, [col][k], swizzled

    const int tid = threadIdx.x;

    for (int i = tid; i < F_IN * 64; i += 512) {
        int k = i >> 6, n = i & 63;
        int byte = (n << 10) + (k << 1);
        byte ^= (n & 7) << 4;
        Bs[byte >> 1] = f2bf(W1[i]);
    }
    if (tid < 64) {
        #pragma unroll
        for (int k = F_IN; k < 512; ++k) {
            int byte = (tid << 10) + (k << 1);
            byte ^= (tid & 7) << 4;
            Bs[byte >> 1] = 0;
        }
    }
    __syncthreads();

    const int lane = tid & 63;
    const int wave = tid >> 6;
    const int lr   = lane & 15;
    const int hi   = lane >> 4;
    const int lk   = hi * 8;

    const int row  = blockIdx.x * 128 + wave * 16 + lr;
    const int rowc = row < N_NODES ? row : N_NODES - 1;
    const float* aptr = x + (size_t)rowc * F_IN + lk;

    f32x4 acc[4] = {};
    float av[4][8];

    #pragma unroll
    for (int pf = 0; pf < 4; ++pf)
        #pragma unroll
        for (int j = 0; j < 8; ++j)
            av[pf][j] = aptr[pf * 32 + j];

    #pragma unroll
    for (int s = 0; s < 16; ++s) {
        bf16x8 a;
        #pragma unroll
        for (int j = 0; j < 8; ++j) a[j] = (short)f2bf(av[s & 3][j]);

        if (s + 4 < 15) {
            #pragma unroll
            for (int j = 0; j < 8; ++j)
                av[s & 3][j] = aptr[(s + 4) * 32 + j];
        } else if (s + 4 == 15) {
            #pragma unroll
            for (int j = 0; j < 8; ++j) {
                int k = 15 * 32 + lk + j;
                av[s & 3][j] = (k < F_IN) ? aptr[15 * 32 + j] : 0.f;
            }
        }

        #pragma unroll
        for (int n = 0; n < 4; ++n) {
            int c = n * 16 + lr;
            int byte = (c << 10) + ((s * 32 + lk) << 1);
            byte ^= (c & 7) << 4;
            bf16x8 b = *(const bf16x8*)((const char*)Bs + byte);
            acc[n] = __builtin_amdgcn_mfma_f32_16x16x32_bf16(a, b, acc[n], 0, 0, 0);
        }
    }

    int rbase = blockIdx.x * 128 + wave * 16 + hi * 4;
    #pragma unroll
    for (int n = 0; n < 4; ++n) {
        int col = n * 16 + lr;
        #pragma unroll
        for (int r = 0; r < 4; ++r) {
            int grow = rbase + r;
            if (grow < N_NODES) xh1b[(size_t)grow * D1 + col] = f2bf(acc[n][r]);
        }
    }
}

// ---------------------------------------------------------------------------
// A1: per-(node,head) attention coefficients for layer 1 (bf16 features)
// ---------------------------------------------------------------------------
__global__ void a1k(const unsigned short* __restrict__ xh1b,
                    const float* __restrict__ att_s, const float* __restrict__ att_d,
                    const int* __restrict__ idxp,
                    float* __restrict__ a_src, float* __restrict__ a_dst) {
    int gid = blockIdx.x * blockDim.x + threadIdx.x;
    if (gid >= N_NODES * H1) return;
    int n = gid >> 3, h = gid & 7;
    float sign = (idxp[0] == 1) ? -1.f : 1.f;
    uint4 u = *(const uint4*)(xh1b + (size_t)n * D1 + h * C1);
    float v[8];
    v[0] = bf2f((unsigned short)(u.x & 0xffff)); v[1] = bf2f((unsigned short)(u.x >> 16));
    v[2] = bf2f((unsigned short)(u.y & 0xffff)); v[3] = bf2f((unsigned short)(u.y >> 16));
    v[4] = bf2f((unsigned short)(u.z & 0xffff)); v[5] = bf2f((unsigned short)(u.z >> 16));
    v[6] = bf2f((unsigned short)(u.w & 0xffff)); v[7] = bf2f((unsigned short)(u.w >> 16));
    float ss = 0.f, sd = 0.f;
    #pragma unroll
    for (int c = 0; c < C1; ++c) {
        ss += v[c] * att_s[h * C1 + c];
        sd += v[c] * att_d[h * C1 + c];
    }
    a_src[gid] = sign * ss;
    a_dst[gid] = sign * sd;
}

// ---------------------------------------------------------------------------
// CSR build: block-aggregated two-level binning — unchanged from R10.
// ---------------------------------------------------------------------------
__global__ __launch_bounds__(256) void bc1(const int* __restrict__ ei,
                                           int* __restrict__ gcnt) {
    __shared__ int h[NBUCK];
    for (int i = threadIdx.x; i < NBUCK; i += 256) h[i] = 0;
    __syncthreads();
    for (int e = blockIdx.x * 256 + threadIdx.x; e < N_EDGES; e += BINBLK * 256)
        atomicAdd(&h[ei[N_EDGES + e] >> BSH], 1);
    __syncthreads();
    for (int i = threadIdx.x; i < NBUCK; i += 256)
        if (h[i]) atomicAdd(&gcnt[i], h[i]);
}

__global__ __launch_bounds__(256) void bc2(const int* __restrict__ gcnt,
                                           int* __restrict__ bbase,
                                           int* __restrict__ bcur,
                                           int* __restrict__ rowptr) {
    __shared__ int s[256];
    int t = threadIdx.x;
    int v = (t < NBUCK) ? gcnt[t] : 0;
    s[t] = v;
    __syncthreads();
    for (int off = 1; off < 256; off <<= 1) {
        int x = 0;
        if (t >= off) x = s[t - off];
        __syncthreads();
        if (t >= off) s[t] += x;
        __syncthreads();
    }
    if (t < NBUCK) { int e = s[t] - v; bbase[t] = e; bcur[t] = e; }
    if (t == 0)    { bbase[NBUCK] = N_EDGES; rowptr[N_NODES] = N_EDGES; }
}

__global__ __launch_bounds__(256) void bc3(const int* __restrict__ ei,
                                           int* __restrict__ bcur,
                                           unsigned* __restrict__ tmp) {
    __shared__ int h[NBUCK];
    __shared__ int base[NBUCK];
    for (int i = threadIdx.x; i < NBUCK; i += 256) h[i] = 0;
    __syncthreads();
    for (int e = blockIdx.x * 256 + threadIdx.x; e < N_EDGES; e += BINBLK * 256)
        atomicAdd(&h[ei[N_EDGES + e] >> BSH], 1);
    __syncthreads();
    for (int i = threadIdx.x; i < NBUCK; i += 256) {
        int c = h[i];
        base[i] = c ? atomicAdd(&bcur[i], c) : 0;
        h[i] = 0;
    }
    __syncthreads();
    for (int e = blockIdx.x * 256 + threadIdx.x; e < N_EDGES; e += BINBLK * 256) {
        int s = ei[e], d = ei[N_EDGES + e];
        int b = d >> BSH;
        int r = atomicAdd(&h[b], 1);
        tmp[base[b] + r] = ((unsigned)s << BSH) | (unsigned)(d & 511);
    }
}

__global__ __launch_bounds__(256) void bc4(const unsigned* __restrict__ tmp,
                                           const int* __restrict__ bbase,
                                           int* __restrict__ rowptr,
                                           int* __restrict__ ssrc) {
    __shared__ int cnt[512], ofs[512], sc[256];
    const int b = blockIdx.x, t = threadIdx.x;
    const int lo = bbase[b], hi = bbase[b + 1];
    cnt[t] = 0; cnt[t + 256] = 0;
    __syncthreads();
    for (int i = lo + t; i < hi; i += 256)
        atomicAdd(&cnt[tmp[i] & 511], 1);
    __syncthreads();
    int v0 = cnt[2 * t], v1 = cnt[2 * t + 1];
    int sum = v0 + v1;
    sc[t] = sum;
    __syncthreads();
    for (int off = 1; off < 256; off <<= 1) {
        int x = 0;
        if (t >= off) x = sc[t - off];
        __syncthreads();
        if (t >= off) sc[t] += x;
        __syncthreads();
    }
    int pre = sc[t] - sum;
    int n0 = (b << BSH) + 2 * t;
    int base0 = lo + pre, base1 = base0 + v0;
    if (n0 < N_NODES)     rowptr[n0]     = base0;
    if (n0 + 1 < N_NODES) rowptr[n0 + 1] = base1;
    ofs[2 * t] = base0; ofs[2 * t + 1] = base1;
    __syncthreads();
    for (int i = lo + t; i < hi; i += 256) {
        unsigned v = tmp[i];
        int p = atomicAdd(&ofs[v & 511], 1);
        ssrc[p] = (int)(v >> BSH);
    }
}

// ---------------------------------------------------------------------------
// AGG1: one wave per destination; 4 chains, loop unrolled 2x -> 8 gathers
// in flight per wave.
// ---------------------------------------------------------------------------
__global__ __launch_bounds__(256) void agg1(const int* __restrict__ rowptr,
                                            const int* __restrict__ ssrc,
                                            const unsigned short* __restrict__ xh1b,
                                            const float* __restrict__ a_src,
                                            const float* __restrict__ a_dst,
                                            unsigned short* __restrict__ hb) {
    int wid  = (blockIdx.x * 256 + threadIdx.x) >> 6;
    int lane = threadIdx.x & 63;
    if (wid >= N_NODES) return;
    const int d  = wid;
    const int li = lane & 15;
    const int q  = lane >> 4;
    const int hh = li >> 1;

    const float adh = a_dst[d * H1 + hh];
    float a0 = 0.f, a1 = 0.f, a2 = 0.f, a3 = 0.f, den = 0.f;
    if (q == 0) {
        float e0 = __expf(lrelu(a_src[d * H1 + hh] + adh));
        ushort4 v = *(const ushort4*)&xh1b[(size_t)d * D1 + (li << 2)];
        a0 = e0 * bf2f(v.x); a1 = e0 * bf2f(v.y);
        a2 = e0 * bf2f(v.z); a3 = e0 * bf2f(v.w);
        den = e0;
    }

    const int beg = rowptr[d], end = rowptr[d + 1];
    int p = beg + q;
    // 2x unrolled: two independent gathers in flight per chain
    for (; p + 4 < end; p += 8) {
        int s0 = ssrc[p];
        int s1 = ssrc[p + 4];
        float as0 = a_src[s0 * H1 + hh];
        float as1 = a_src[s1 * H1 + hh];
        ushort4 v0 = *(const ushort4*)&xh1b[(size_t)s0 * D1 + (li << 2)];
        ushort4 v1 = *(const ushort4*)&xh1b[(size_t)s1 * D1 + (li << 2)];
        float e0 = __expf(lrelu(as0 + adh));
        float e1 = __expf(lrelu(as1 + adh));
        a0 = fmaf(e0, bf2f(v0.x), a0);
        a1 = fmaf(e0, bf2f(v0.y), a1);
        a2 = fmaf(e0, bf2f(v0.z), a2);
        a3 = fmaf(e0, bf2f(v0.w), a3);
        den += e0;
        a0 = fmaf(e1, bf2f(v1.x), a0);
        a1 = fmaf(e1, bf2f(v1.y), a1);
        a2 = fmaf(e1, bf2f(v1.z), a2);
        a3 = fmaf(e1, bf2f(v1.w), a3);
        den += e1;
    }
    if (p < end) {
        int s = ssrc[p];
        float e = __expf(lrelu(a_src[s * H1 + hh] + adh));
        ushort4 v = *(const ushort4*)&xh1b[(size_t)s * D1 + (li << 2)];
        a0 = fmaf(e, bf2f(v.x), a0);
        a1 = fmaf(e, bf2f(v.y), a1);
        a2 = fmaf(e, bf2f(v.z), a2);
        a3 = fmaf(e, bf2f(v.w), a3);
        den += e;
    }

    a0 += __shfl_xor(a0, 16); a0 += __shfl_xor(a0, 32);
    a1 += __shfl_xor(a1, 16); a1 += __shfl_xor(a1, 32);
    a2 += __shfl_xor(a2, 16); a2 += __shfl_xor(a2, 32);
    a3 += __shfl_xor(a3, 16); a3 += __shfl_xor(a3, 32);
    den += __shfl_xor(den, 16); den += __shfl_xor(den, 32);

    if (lane < 16) {
        float inv = 1.f / (den + 1e-16f);
        float v0 = a0 * inv, v1 = a1 * inv, v2 = a2 * inv, v3 = a3 * inv;
        v0 = v0 > 0.f ? v0 : (__expf(v0) - 1.f);
        v1 = v1 > 0.f ? v1 : (__expf(v1) - 1.f);
        v2 = v2 > 0.f ? v2 : (__expf(v2) - 1.f);
        v3 = v3 > 0.f ? v3 : (__expf(v3) - 1.f);
        ushort4 r;
        r.x = f2bf(v0); r.y = f2bf(v1); r.z = f2bf(v2); r.w = f2bf(v3);
        *(ushort4*)&hb[(size_t)d * D1 + (li << 2)] = r;
    }
}

// ---------------------------------------------------------------------------
// GEMM2: xh2b[N,40] = bf16( h[N,64] @ W2[64,40] )
// ---------------------------------------------------------------------------
__global__ void gemm2(const unsigned short* __restrict__ hb,
                      const float* __restrict__ W2,
                      unsigned short* __restrict__ xh2b) {
    int gid = blockIdx.x * blockDim.x + threadIdx.x;
    if (gid >= N_NODES * NCLS) return;
    int n = gid / NCLS, c = gid % NCLS;
    const uint4* hr = (const uint4*)(hb + (size_t)n * D1);
    float s = 0.f;
    #pragma unroll
    for (int q = 0; q < 8; ++q) {
        uint4 u = hr[q];
        int k = q * 8;
        s = fmaf(bf2f((unsigned short)(u.x & 0xffff)), W2[(k + 0) * NCLS + c], s);
        s = fmaf(bf2f((unsigned short)(u.x >> 16)),    W2[(k + 1) * NCLS + c], s);
        s = fmaf(bf2f((unsigned short)(u.y & 0xffff)), W2[(k + 2) * NCLS + c], s);
        s = fmaf(bf2f((unsigned short)(u.y >> 16)),    W2[(k + 3) * NCLS + c], s);
        s = fmaf(bf2f((unsigned short)(u.z & 0xffff)), W2[(k + 4) * NCLS + c], s);
        s = fmaf(bf2f((unsigned short)(u.z >> 16)),    W2[(k + 5) * NCLS + c], s);
        s = fmaf(bf2f((unsigned short)(u.w & 0xffff)), W2[(k + 6) * NCLS + c], s);
        s = fmaf(bf2f((unsigned short)(u.w >> 16)),    W2[(k + 7) * NCLS + c], s);
    }
    xh2b[gid] = f2bf(s);
}

// ---------------------------------------------------------------------------
// A2: per-node attention coefficients for layer 2 (bf16 features)
// ---------------------------------------------------------------------------
__global__ void a2k(const unsigned short* __restrict__ xh2b,
                    const float* __restrict__ att_s2, const float* __restrict__ att_d2,
                    const int* __restrict__ idxp,
                    float* __restrict__ a_src2, float* __restrict__ a_dst2) {
    int n = blockIdx.x * blockDim.x + threadIdx.x;
    if (n >= N_NODES) return;
    float sign = (idxp[0] == 1) ? -1.f : 1.f;
    const uint4* xr = (const uint4*)(xh2b + (size_t)n * NCLS);
    float ss = 0.f, sd = 0.f;
    #pragma unroll
    for (int q = 0; q < 5; ++q) {
        uint4 u = xr[q];
        int k = q * 8;
        float v[8];
        v[0] = bf2f((unsigned short)(u.x & 0xffff)); v[1] = bf2f((unsigned short)(u.x >> 16));
        v[2] = bf2f((unsigned short)(u.y & 0xffff)); v[3] = bf2f((unsigned short)(u.y >> 16));
        v[4] = bf2f((unsigned short)(u.z & 0xffff)); v[5] = bf2f((unsigned short)(u.z >> 16));
        v[6] = bf2f((unsigned short)(u.w & 0xffff)); v[7] = bf2f((unsigned short)(u.w >> 16));
        #pragma unroll
        for (int j = 0; j < 8; ++j) {
            ss += v[j] * att_s2[k + j];
            sd += v[j] * att_d2[k + j];
        }
    }
    a_src2[n] = sign * ss;
    a_dst2[n] = sign * sd;
}

// ---------------------------------------------------------------------------
// AGG2: one wave per destination; 4 chains, loop unrolled 2x.
// ---------------------------------------------------------------------------
__global__ __launch_bounds__(256) void agg2(const int* __restrict__ rowptr,
                                            const int* __restrict__ ssrc,
                                            const unsigned short* __restrict__ xh2b,
                                            const float* __restrict__ a_src2,
                                            const float* __restrict__ a_dst2,
                                            const float* __restrict__ bias2,
                                            float* __restrict__ out) {
    int wid  = (blockIdx.x * 256 + threadIdx.x) >> 6;
    int lane = threadIdx.x & 63;
    if (wid >= N_NODES) return;
    const int d  = wid;
    const int li = lane & 15;
    const int q  = lane >> 4;
    const bool act = li < (NCLS / 4);

    const float adh = a_dst2[d];
    float a0 = 0.f, a1 = 0.f, a2 = 0.f, a3 = 0.f, den = 0.f;
    if (q == 0) {
        float e0 = __expf(lrelu(a_src2[d] + adh));
        if (act) {
            ushort4 v = *(const ushort4*)&xh2b[(size_t)d * NCLS + (li << 2)];
            a0 = e0 * bf2f(v.x); a1 = e0 * bf2f(v.y);
            a2 = e0 * bf2f(v.z); a3 = e0 * bf2f(v.w);
        }
        den = e0;
    }

    const int beg = rowptr[d], end = rowptr[d + 1];
    int p = beg + q;
    for (; p + 4 < end; p += 8) {
        int s0 = ssrc[p];
        int s1 = ssrc[p + 4];
        float as0 = a_src2[s0];
        float as1 = a_src2[s1];
        ushort4 v0, v1;
        if (act) {
            v0 = *(const ushort4*)&xh2b[(size_t)s0 * NCLS + (li << 2)];
            v1 = *(const ushort4*)&xh2b[(size_t)s1 * NCLS + (li << 2)];
        }
        float e0 = __expf(lrelu(as0 + adh));
        float e1 = __expf(lrelu(as1 + adh));
        if (act) {
            a0 = fmaf(e0, bf2f(v0.x), a0);
            a1 = fmaf(e0, bf2f(v0.y), a1);
            a2 = fmaf(e0, bf2f(v0.z), a2);
            a3 = fmaf(e0, bf2f(v0.w), a3);
            a0 = fmaf(e1, bf2f(v1.x), a0);
            a1 = fmaf(e1, bf2f(v1.y), a1);
            a2 = fmaf(e1, bf2f(v1.z), a2);
            a3 = fmaf(e1, bf2f(v1.w), a3);
        }
        den += e0 + e1;
    }
    if (p < end) {
        int s = ssrc[p];
        float e = __expf(lrelu(a_src2[s] + adh));
        if (act) {
            ushort4 v = *(const ushort4*)&xh2b[(size_t)s * NCLS + (li << 2)];
            a0 = fmaf(e, bf2f(v.x), a0);
            a1 = fmaf(e, bf2f(v.y), a1);
            a2 = fmaf(e, bf2f(v.z), a2);
            a3 = fmaf(e, bf2f(v.w), a3);
        }
        den += e;
    }

    a0 += __shfl_xor(a0, 16); a0 += __shfl_xor(a0, 32);
    a1 += __shfl_xor(a1, 16); a1 += __shfl_xor(a1, 32);
    a2 += __shfl_xor(a2, 16); a2 += __shfl_xor(a2, 32);
    a3 += __shfl_xor(a3, 16); a3 += __shfl_xor(a3, 32);
    den += __shfl_xor(den, 16); den += __shfl_xor(den, 32);

    if (lane < 16 && act) {
        float inv = 1.f / (den + 1e-16f);
        float4 bv = *(const float4*)&bias2[li << 2];
        float4 r;
        r.x = a0 * inv + bv.x;
        r.y = a1 * inv + bv.y;
        r.z = a2 * inv + bv.z;
        r.w = a3 * inv + bv.w;
        *(float4*)&out[(size_t)d * NCLS + (li << 2)] = r;
    }
}

// ---------------------------------------------------------------------------
extern "C" void kernel_launch(void* const* d_in, const int* in_sizes, int n_in,
                              void* d_out, int out_size, void* d_ws, size_t ws_size,
                              hipStream_t stream) {
    const float* x    = (const float*)d_in[0];
    const float* W1   = (const float*)d_in[1];
    const float* as1w = (const float*)d_in[2];
    const float* ad1w = (const float*)d_in[3];
    const float* W2   = (const float*)d_in[4];
    const float* as2w = (const float*)d_in[5];
    const float* ad2w = (const float*)d_in[6];
    const float* b2   = (const float*)d_in[7];
    const int*   ei   = (const int*)d_in[8];
    const int*   idxp = (const int*)d_in[9];
    float* out = (float*)d_out;

    // workspace layout
    unsigned short* xh1b = (unsigned short*)d_ws;        // [N*64] bf16
    unsigned short* hb   = xh1b + (size_t)N_NODES * D1;  // [N*64] bf16
    unsigned short* xh2b = hb + (size_t)N_NODES * D1;    // [N*40] bf16
    float* as1 = (float*)(xh2b + (size_t)N_NODES * NCLS);
    float* ad1 = as1 + (size_t)N_NODES * H1;
    float* as2 = ad1 + (size_t)N_NODES * H1;             // [N]
    float* ad2 = as2 + N_NODES;
    int* gcnt   = (int*)(ad2 + N_NODES);                 // [NBUCK]
    int* bbase  = gcnt + NBUCK;                          // [NBUCK+1]
    int* bcur   = bbase + (NBUCK + 1);                   // [NBUCK]
    int* rowptr = bcur + NBUCK;                          // [N+1]
    unsigned* tmp = (unsigned*)(rowptr + (N_NODES + 1)); // [E]
    int* ssrc   = (int*)(tmp + N_EDGES);                 // [E]

    // ---- CSR build (block-aggregated two-level binning) ----
    hipMemsetAsync(gcnt, 0, (size_t)NBUCK * sizeof(int), stream);
    bc1<<<BINBLK, 256, 0, stream>>>(ei, gcnt);
    bc2<<<1, 256, 0, stream>>>(gcnt, bbase, bcur, rowptr);
    bc3<<<BINBLK, 256, 0, stream>>>(ei, bcur, tmp);
    bc4<<<NBUCK, 256, 0, stream>>>(tmp, bbase, rowptr, ssrc);

    // ---- layer 1 ----
    gemm1<<<(N_NODES + 127) / 128, 512, 0, stream>>>(x, W1, xh1b);
    a1k<<<(N_NODES * H1 + 255) / 256, 256, 0, stream>>>(xh1b, as1w, ad1w, idxp, as1, ad1);
    agg1<<<(N_NODES * 64 + 255) / 256, 256, 0, stream>>>(rowptr, ssrc, xh1b, as1, ad1, hb);

    // ---- layer 2 ----
    gemm2<<<(N_NODES * NCLS + 255) / 256, 256, 0, stream>>>(hb, W2, xh2b);
    a2k<<<(N_NODES + 255) / 256, 256, 0, stream>>>(xh2b, as2w, ad2w, idxp, as2, ad2);
    agg2<<<(N_NODES * 64 + 255) / 256, 256, 0, stream>>>(rowptr, ssrc, xh2b, as2, ad2, b2, out);
}